// Round 1
// baseline (106.842 us; speedup 1.0000x reference)
//
#include <hip/hip_runtime.h>
#include <cstdint>

#define BSZ 512   // batch
#define CSZ 256   // concepts

// ---------------- block reduction helpers (256 threads) ----------------
__device__ __forceinline__ float block_reduce_max256(float v, float* scratch) {
    int tid = threadIdx.x;
    scratch[tid] = v;
    __syncthreads();
    for (int s = 128; s > 0; s >>= 1) {
        if (tid < s) scratch[tid] = fmaxf(scratch[tid], scratch[tid + s]);
        __syncthreads();
    }
    float r = scratch[0];
    __syncthreads();
    return r;
}

__device__ __forceinline__ float block_reduce_sum256(float v, float* scratch) {
    int tid = threadIdx.x;
    scratch[tid] = v;
    __syncthreads();
    for (int s = 128; s > 0; s >>= 1) {
        if (tid < s) scratch[tid] += scratch[tid + s];
        __syncthreads();
    }
    float r = scratch[0];
    __syncthreads();
    return r;
}

// ---------------- kernels ----------------

// acc[0] = sum over both matrices of (lse_row - diag)
// acc[1] = sum masked BCE loss ; acc[2] = mask count ; acc[3] = KL sum
__global__ void init_ws_kernel(float* acc) {
    if (threadIdx.x < 8) acc[threadIdx.x] = 0.0f;
}

// One block per row; blocks [0,512) -> image matrix, [512,1024) -> text matrix.
__global__ void clip_kernel(const float* __restrict__ img,
                            const float* __restrict__ txt,
                            float* __restrict__ acc) {
    __shared__ float scratch[256];
    int row = blockIdx.x & (BSZ - 1);
    const float* mat = (blockIdx.x < BSZ) ? img : txt;
    const float* r = mat + (size_t)row * BSZ;
    int tid = threadIdx.x;
    float x0 = r[tid];
    float x1 = r[tid + 256];
    float mx = block_reduce_max256(fmaxf(x0, x1), scratch);
    float se = block_reduce_sum256(__expf(x0 - mx) + __expf(x1 - mx), scratch);
    if (tid == 0) {
        float lse = mx + logf(se);
        atomicAdd(&acc[0], lse - r[row]);
    }
}

// One block per batch row. BCE + mask count + bit-pack w (w=1 iff mc==1).
__global__ void concept_kernel(const float* __restrict__ clog,
                               const int* __restrict__ mc,
                               float* __restrict__ acc,
                               unsigned long long* __restrict__ packed) {
    __shared__ float scratch[256];
    int i = blockIdx.x, tid = threadIdx.x;
    int m = mc[i * CSZ + tid];
    float x = clog[i * CSZ + tid];
    float maskf = (m != -1) ? 1.0f : 0.0f;
    float t = (m == 1) ? 1.0f : 0.0f;
    // stable logaddexp(0,x) - x*t
    float loss = (fmaxf(x, 0.0f) + log1pf(expf(-fabsf(x))) - x * t) * maskf;
    float ls = block_reduce_sum256(loss, scratch);
    float ms = block_reduce_sum256(maskf, scratch);
    if (tid == 0) {
        atomicAdd(&acc[1], ls);
        atomicAdd(&acc[2], ms);
    }
    unsigned long long bal = __ballot(m == 1);
    if ((tid & 63) == 0) packed[i * 4 + (tid >> 6)] = bal;
}

// One block per row i: Jaccard sims via popcount over bit-packed w,
// softmax(sim/T) targets, KL vs log_softmax(csim row).
__global__ void sim_kernel(const float* __restrict__ csim,
                           const unsigned long long* __restrict__ packed,
                           float* __restrict__ acc) {
    __shared__ unsigned long long wb[BSZ * 4];  // 16 KB: all packed rows
    __shared__ float sdat[BSZ];                 // sim/T values
    __shared__ float cdat[BSZ];                 // csim row
    __shared__ float scratch[256];
    int i = blockIdx.x, tid = threadIdx.x;
    for (int k = tid; k < BSZ * 4; k += 256) wb[k] = packed[k];
    __syncthreads();
    unsigned long long a0 = wb[i * 4 + 0], a1 = wb[i * 4 + 1];
    unsigned long long a2 = wb[i * 4 + 2], a3 = wb[i * 4 + 3];
    for (int j = tid; j < BSZ; j += 256) {
        unsigned long long b0 = wb[j * 4 + 0], b1 = wb[j * 4 + 1];
        unsigned long long b2 = wb[j * 4 + 2], b3 = wb[j * 4 + 3];
        int inter = __popcll(a0 & b0) + __popcll(a1 & b1) + __popcll(a2 & b2) + __popcll(a3 & b3);
        int uni   = __popcll(a0 | b0) + __popcll(a1 | b1) + __popcll(a2 | b2) + __popcll(a3 | b3);
        float sim = (uni > 0) ? ((float)inter / (float)uni) : 0.0f;
        sdat[j] = sim / 0.07f;
        cdat[j] = csim[(size_t)i * BSZ + j];
    }
    __syncthreads();
    float s0 = sdat[tid], s1 = sdat[tid + 256];
    float c0 = cdat[tid], c1 = cdat[tid + 256];
    float mx_s = block_reduce_max256(fmaxf(s0, s1), scratch);
    float Zs = block_reduce_sum256(expf(s0 - mx_s) + expf(s1 - mx_s), scratch);
    float lse_s = mx_s + logf(Zs);
    float mx_c = block_reduce_max256(fmaxf(c0, c1), scratch);
    float Zc = block_reduce_sum256(expf(c0 - mx_c) + expf(c1 - mx_c), scratch);
    float lse_c = mx_c + logf(Zc);
    float t0 = expf(s0 - lse_s), t1 = expf(s1 - lse_s);
    float kl0 = t0 * ((s0 - lse_s) - (c0 - lse_c));
    float kl1 = t1 * ((s1 - lse_s) - (c1 - lse_c));
    float kl = block_reduce_sum256(kl0 + kl1, scratch);
    if (tid == 0) atomicAdd(&acc[3], kl);
}

__global__ void final_kernel(const float* __restrict__ acc, float* __restrict__ out) {
    if (threadIdx.x == 0) {
        float clip_loss = acc[0] / (2.0f * BSZ);          // mean over both matrices, /2
        float concept_loss = acc[1] / (acc[2] + 1e-8f);
        float kl = acc[3] / (float)BSZ;                   // batchmean
        out[0] = clip_loss + 0.5f * concept_loss + 0.3f * kl;
    }
}

extern "C" void kernel_launch(void* const* d_in, const int* in_sizes, int n_in,
                              void* d_out, int out_size, void* d_ws, size_t ws_size,
                              hipStream_t stream) {
    const float* logits_img = (const float*)d_in[0];   // [512,512]
    const float* logits_txt = (const float*)d_in[1];   // [512,512]
    const float* clog       = (const float*)d_in[2];   // [512,256]
    const float* csim       = (const float*)d_in[3];   // [512,512]
    const int*   mc         = (const int*)d_in[4];     // [512,256]
    float* out = (float*)d_out;

    float* acc = (float*)d_ws;                                         // 8 floats
    unsigned long long* packed = (unsigned long long*)((char*)d_ws + 256); // 16 KB

    init_ws_kernel<<<1, 64, 0, stream>>>(acc);
    clip_kernel<<<2 * BSZ, 256, 0, stream>>>(logits_img, logits_txt, acc);
    concept_kernel<<<BSZ, 256, 0, stream>>>(clog, mc, acc, packed);
    sim_kernel<<<BSZ, 256, 0, stream>>>(csim, packed, acc);
    final_kernel<<<1, 64, 0, stream>>>(acc, out);
}